// Round 5
// baseline (854.867 us; speedup 1.0000x reference)
//
#include <hip/hip_runtime.h>
#include <cstddef>
#include <cstdint>

constexpr int B = 4, S = 2048, E = 1024, H = 16, D = 64;
constexpr int M_ROWS = B * S;   // 8192

typedef __bf16 bf16x8 __attribute__((ext_vector_type(8)));
typedef float  f32x4  __attribute__((ext_vector_type(4)));

__device__ __forceinline__ unsigned short f2bf(float x) {
    union { float f; uint32_t u; } v; v.f = x;
    uint32_t r = v.u + 0x7fff + ((v.u >> 16) & 1);   // RNE
    return (unsigned short)(r >> 16);
}
__device__ __forceinline__ float bf2f(unsigned short h) {
    union { uint32_t u; float f; } v; v.u = (uint32_t)h << 16; return v.f;
}

// ---------------------------------------------------------------------------
// Split fp32 -> (hi, lo) bf16 for x (4096 blks), w1 (1536 blks), w2 (512 blks).
// ---------------------------------------------------------------------------
__global__ __launch_bounds__(256)
void cvt3(const float* __restrict__ x,  unsigned short* __restrict__ xhi,  unsigned short* __restrict__ xlo,
          const float* __restrict__ w1, unsigned short* __restrict__ w1hi, unsigned short* __restrict__ w1lo,
          const float* __restrict__ w2, unsigned short* __restrict__ w2hi, unsigned short* __restrict__ w2lo)
{
    const int bid = blockIdx.x;
    const float* s; unsigned short *ph, *pl; size_t idx;
    if (bid < 4096)      { s = x;  ph = xhi;  pl = xlo;  idx = (size_t)bid * 256 + threadIdx.x; }
    else if (bid < 5632) { s = w1; ph = w1hi; pl = w1lo; idx = (size_t)(bid - 4096) * 256 + threadIdx.x; }
    else                 { s = w2; ph = w2hi; pl = w2lo; idx = (size_t)(bid - 5632) * 256 + threadIdx.x; }
    const float4* s4 = (const float4*)s;
    float4 v0 = s4[idx * 2], v1 = s4[idx * 2 + 1];
    float f[8] = { v0.x, v0.y, v0.z, v0.w, v1.x, v1.y, v1.z, v1.w };
    unsigned short hh[8], ll[8];
    #pragma unroll
    for (int j = 0; j < 8; ++j) {
        hh[j] = f2bf(f[j]);
        ll[j] = f2bf(f[j] - bf2f(hh[j]));
    }
    ((int4*)ph)[idx] = *(const int4*)hh;
    ((int4*)pl)[idx] = *(const int4*)ll;
}

// ---------------------------------------------------------------------------
// Split-bf16 MFMA GEMM: C[M,N] = (Ahi+Alo)[M,K] @ (Whi+Wlo)[N,K]^T + bias
//   via Ahi*Whi + Ahi*Wlo + Alo*Whi (fp32 accum).
// 128x128 tile, BK=32, 4 waves (2x2 of 64x64).
// Staging: global->reg (issued BEFORE barrier) -> ds_write_b128 (race-safe).
// MODE 0: C fp32 [M,N] + bias (direct stores: full 64B sectors)
// MODE 1: QKV scatter via per-wave LDS repack -> fully coalesced int4 stores:
//   q,k -> bf16 [B,H,S,D]; v -> bf16 [B,H,D,S]
// ---------------------------------------------------------------------------
template<int MODE>
__global__ __launch_bounds__(256)
void gemm_mfma(const unsigned short* __restrict__ Ahi, const unsigned short* __restrict__ Alo,
               const unsigned short* __restrict__ Whi, const unsigned short* __restrict__ Wlo,
               const float* __restrict__ bias, float* __restrict__ C,
               unsigned short* __restrict__ qd, unsigned short* __restrict__ kd,
               unsigned short* __restrict__ vd, int M, int N, int K)
{
    __shared__ __align__(16) unsigned short lds4[4][128 * 32]; // Ahi, Alo, Whi, Wlo

    const int t    = threadIdx.x;
    const int wid  = t >> 6, lane = t & 63;
    const int l16  = lane & 15, lg = lane >> 4;
    const int wr   = wid >> 1, wc = wid & 1;
    const int m0   = blockIdx.y * 128;
    const int n0   = blockIdx.x * 128;

    // this thread's two staged chunks per array: c = half*256 + t
    int srow[2], soff[2];
    #pragma unroll
    for (int half = 0; half < 2; ++half) {
        int c = half * 256 + t;
        int row = c >> 2, cc = c & 3;
        int scc = cc ^ ((row >> 1) & 3);     // pre-swizzled source chunk
        srow[half] = row;
        soff[half] = scc * 8;
    }

    f32x4 acc[4][4];
    #pragma unroll
    for (int mi = 0; mi < 4; ++mi)
        #pragma unroll
        for (int ni = 0; ni < 4; ++ni) acc[mi][ni] = (f32x4){0.f, 0.f, 0.f, 0.f};

    for (int k0 = 0; k0 < K; k0 += 32) {
        const unsigned short* gsrc[4] = {
            Ahi + (size_t)m0 * K + k0, Alo + (size_t)m0 * K + k0,
            Whi + (size_t)n0 * K + k0, Wlo + (size_t)n0 * K + k0 };

        // issue all global loads first (overlap with barrier wait / other waves)
        int4 stg[8];
        #pragma unroll
        for (int arr = 0; arr < 4; ++arr)
            #pragma unroll
            for (int half = 0; half < 2; ++half)
                stg[arr * 2 + half] =
                    *(const int4*)(gsrc[arr] + (size_t)srow[half] * K + soff[half]);

        __syncthreads();    // previous iteration's LDS reads complete
        #pragma unroll
        for (int arr = 0; arr < 4; ++arr)
            #pragma unroll
            for (int half = 0; half < 2; ++half) {
                int c = half * 256 + t;
                *(int4*)&lds4[arr][c * 8] = stg[arr * 2 + half];
            }
        __syncthreads();

        bf16x8 ahi[4], alo[4], bhi[4], blo[4];
        #pragma unroll
        for (int mi = 0; mi < 4; ++mi) {
            int arow = wr * 64 + mi * 16 + l16;
            int co   = ((lg ^ ((arow >> 1) & 3)) << 3);
            ahi[mi] = *(const bf16x8*)&lds4[0][arow * 32 + co];
            alo[mi] = *(const bf16x8*)&lds4[1][arow * 32 + co];
        }
        #pragma unroll
        for (int ni = 0; ni < 4; ++ni) {
            int brow = wc * 64 + ni * 16 + l16;
            int co   = ((lg ^ ((brow >> 1) & 3)) << 3);
            bhi[ni] = *(const bf16x8*)&lds4[2][brow * 32 + co];
            blo[ni] = *(const bf16x8*)&lds4[3][brow * 32 + co];
        }
        #pragma unroll
        for (int mi = 0; mi < 4; ++mi)
            #pragma unroll
            for (int ni = 0; ni < 4; ++ni) {
                acc[mi][ni] = __builtin_amdgcn_mfma_f32_16x16x32_bf16(ahi[mi], bhi[ni], acc[mi][ni], 0, 0, 0);
                acc[mi][ni] = __builtin_amdgcn_mfma_f32_16x16x32_bf16(ahi[mi], blo[ni], acc[mi][ni], 0, 0, 0);
                acc[mi][ni] = __builtin_amdgcn_mfma_f32_16x16x32_bf16(alo[mi], bhi[ni], acc[mi][ni], 0, 0, 0);
            }
        // no trailing barrier: next iteration's pre-store barrier protects reads
    }

    __syncthreads();   // all waves done with lds4 (uniform; before epilogue reuse)

    const int colblk = n0 + wc * 64;
    if constexpr (MODE == 0) {
        #pragma unroll
        for (int mi = 0; mi < 4; ++mi)
            #pragma unroll
            for (int r = 0; r < 4; ++r) {
                int row = m0 + wr * 64 + mi * 16 + lg * 4 + r;
                #pragma unroll
                for (int ni = 0; ni < 4; ++ni) {
                    int col = colblk + ni * 16 + l16;
                    C[(size_t)row * N + col] = acc[mi][ni][r] + bias[col];
                }
            }
    } else {
        // per-wave 8KB repack tile (reuses staging LDS; wave-private => no barrier)
        unsigned short* et = &lds4[0][0] + wid * 4096;
        const int which = colblk >> 10;            // 0:q 1:k 2:v (uniform per wave)
        const int e0    = colblk & (E - 1);
        const int h_    = e0 >> 6;                 // colblk%64==0 -> one head/wave
        const int rowg0 = m0 + wr * 64;            // 64 consecutive s, single b
        const int b_    = rowg0 >> 11;
        const int s0g   = rowg0 & (S - 1);
        const int j8    = lane & 7, r8 = lane >> 3;

        if (which < 2) {
            unsigned short* dst = (which == 0) ? qd : kd;
            // store [s][d], 16B-chunk XOR swizzle
            #pragma unroll
            for (int mi = 0; mi < 4; ++mi)
                #pragma unroll
                for (int ni = 0; ni < 4; ++ni) {
                    int dcol = ni * 16 + l16;
                    int ch   = dcol >> 3;
                    float bv = bias[colblk + dcol];
                    #pragma unroll
                    for (int r = 0; r < 4; ++r) {
                        int row = mi * 16 + lg * 4 + r;
                        et[row * 64 + ((ch ^ (row & 7)) << 3) + (dcol & 7)] =
                            f2bf(acc[mi][ni][r] + bv);
                    }
                }
            // read b128 conflict-free; each instr writes 1KB contiguous HBM
            #pragma unroll
            for (int it = 0; it < 8; ++it) {
                int sr = it * 8 + r8;
                int4 vv = *(const int4*)&et[sr * 64 + ((j8 ^ (sr & 7)) << 3)];
                *(int4*)&dst[(((size_t)(b_ * H + h_)) * S + (s0g + sr)) * D + j8 * 8] = vv;
            }
        } else {
            // store transposed T[d][s], b64 writes, same chunk swizzle
            #pragma unroll
            for (int mi = 0; mi < 4; ++mi) {
                int s0l = mi * 16 + lg * 4;
                int ch  = s0l >> 3;
                int off = s0l & 4;
                #pragma unroll
                for (int ni = 0; ni < 4; ++ni) {
                    int dcol = ni * 16 + l16;
                    float bv = bias[colblk + dcol];
                    unsigned short tmp[4];
                    #pragma unroll
                    for (int r = 0; r < 4; ++r) tmp[r] = f2bf(acc[mi][ni][r] + bv);
                    *(uint2*)&et[dcol * 64 + ((ch ^ (dcol & 7)) << 3) + off] = *(const uint2*)tmp;
                }
            }
            #pragma unroll
            for (int it = 0; it < 8; ++it) {
                int dd = it * 8 + r8;
                int4 vv = *(const int4*)&et[dd * 64 + ((j8 ^ (dd & 7)) << 3)];
                *(int4*)&vd[(((size_t)(b_ * H + h_)) * D + dd) * S + s0g + j8 * 8] = vv;
            }
        }
    }
}

// ---------------------------------------------------------------------------
// MFMA flash attention — epilogue writes hi/lo bf16 for the out-proj GEMM.
// ---------------------------------------------------------------------------
__global__ __launch_bounds__(256)
void attn_mfma(const unsigned short* __restrict__ Qb,
               const unsigned short* __restrict__ Kb,
               const unsigned short* __restrict__ Vtb,
               const float* __restrict__ rel,
               unsigned short* __restrict__ AOhi, unsigned short* __restrict__ AOlo)
{
    __shared__ unsigned short lds_k[4096];      // K  [64 k][64 d] swz
    __shared__ unsigned short lds_v[4096];      // Vt [64 d][64 k] swz
    __shared__ unsigned short lds_p[4][1024];   // per-wave P [16 q][64 k] swz

    const int t    = threadIdx.x;
    const int wid  = t >> 6, lane = t & 63;
    const int l16  = lane & 15, lg = lane >> 4;
    const int bh   = blockIdx.y;
    const int q0   = blockIdx.x * 64;
    const int b_   = bh >> 4, h_ = bh & 15;

    const size_t qkoff = (size_t)bh * S * D;
    const size_t vtoff = (size_t)bh * D * S;

    bf16x8 qf[2];
    {
        const unsigned short* qrow = Qb + qkoff + (size_t)(q0 + wid * 16 + l16) * D;
        qf[0] = *(const bf16x8*)(qrow + lg * 8);
        qf[1] = *(const bf16x8*)(qrow + 32 + lg * 8);
    }

    float m_run[4], l_run[4];
    f32x4 o[4];
    #pragma unroll
    for (int r = 0; r < 4; ++r) { m_run[r] = -3.0e38f; l_run[r] = 0.f; }
    #pragma unroll
    for (int dt = 0; dt < 4; ++dt) o[dt] = (f32x4){0.f, 0.f, 0.f, 0.f};

    for (int k0 = 0; k0 < S; k0 += 64) {
        __syncthreads();
        #pragma unroll
        for (int i = 0; i < 2; ++i) {
            int c   = wid * 128 + i * 64 + lane;
            int row = c >> 3, cc = c & 7;
            int sc  = cc ^ (row & 7);
            const unsigned short* gk = Kb  + qkoff + (size_t)(k0 + row) * D + sc * 8;
            *(int4*)&lds_k[c * 8] = *(const int4*)gk;
            const unsigned short* gv = Vtb + vtoff + (size_t)row * S + k0 + sc * 8;
            *(int4*)&lds_v[c * 8] = *(const int4*)gv;
        }
        __syncthreads();

        f32x4 acc[4];
        #pragma unroll
        for (int kt = 0; kt < 4; ++kt) acc[kt] = (f32x4){0.f, 0.f, 0.f, 0.f};
        #pragma unroll
        for (int f = 0; f < 2; ++f) {
            #pragma unroll
            for (int kt = 0; kt < 4; ++kt) {
                int key   = kt * 16 + l16;
                int chunk = (f * 4 + lg) ^ (key & 7);
                bf16x8 kf = *(const bf16x8*)&lds_k[key * 64 + chunk * 8];
                acc[kt] = __builtin_amdgcn_mfma_f32_16x16x32_bf16(qf[f], kf, acc[kt], 0, 0, 0);
            }
        }

        const float* relbase = rel + (size_t)(q0 + wid * 16) * S + k0;
        float p[4][4], ml[4];
        #pragma unroll
        for (int r = 0; r < 4; ++r) ml[r] = -3.0e38f;
        #pragma unroll
        for (int kt = 0; kt < 4; ++kt)
            #pragma unroll
            for (int r = 0; r < 4; ++r) {
                float sv = acc[kt][r] * 0.125f
                         + relbase[(size_t)(lg * 4 + r) * S + kt * 16 + l16];
                p[kt][r] = sv;
                ml[r] = fmaxf(ml[r], sv);
            }
        #pragma unroll
        for (int r = 0; r < 4; ++r) {
            float v = ml[r];
            v = fmaxf(v, __shfl_xor(v, 1));
            v = fmaxf(v, __shfl_xor(v, 2));
            v = fmaxf(v, __shfl_xor(v, 4));
            v = fmaxf(v, __shfl_xor(v, 8));
            ml[r] = v;
        }
        float alpha[4];
        #pragma unroll
        for (int r = 0; r < 4; ++r) {
            float mnew = fmaxf(m_run[r], ml[r]);
            alpha[r] = __expf(m_run[r] - mnew);
            m_run[r] = mnew;
        }
        float lsum[4] = {0.f, 0.f, 0.f, 0.f};
        #pragma unroll
        for (int kt = 0; kt < 4; ++kt)
            #pragma unroll
            for (int r = 0; r < 4; ++r) {
                float e = __expf(p[kt][r] - m_run[r]);
                p[kt][r] = e;
                lsum[r] += e;
            }
        #pragma unroll
        for (int r = 0; r < 4; ++r) {
            float v = lsum[r];
            v += __shfl_xor(v, 1);
            v += __shfl_xor(v, 2);
            v += __shfl_xor(v, 4);
            v += __shfl_xor(v, 8);
            l_run[r] = l_run[r] * alpha[r] + v;
        }

        unsigned short* pw = &lds_p[wid][0];
        #pragma unroll
        for (int kt = 0; kt < 4; ++kt)
            #pragma unroll
            for (int r = 0; r < 4; ++r) {
                int qr = lg * 4 + r;
                int k  = kt * 16 + l16;
                pw[qr * 64 + (((k >> 3) ^ (qr & 7)) << 3) + (k & 7)] = f2bf(p[kt][r]);
            }

        #pragma unroll
        for (int dt = 0; dt < 4; ++dt)
            #pragma unroll
            for (int r = 0; r < 4; ++r)
                o[dt][r] *= alpha[r];

        #pragma unroll
        for (int f = 0; f < 2; ++f) {
            int pchunk = (f * 4 + lg) ^ (l16 & 7);
            bf16x8 pf = *(const bf16x8*)&pw[l16 * 64 + pchunk * 8];
            #pragma unroll
            for (int dt = 0; dt < 4; ++dt) {
                int d      = dt * 16 + l16;
                int vchunk = (f * 4 + lg) ^ (d & 7);
                bf16x8 vf  = *(const bf16x8*)&lds_v[d * 64 + vchunk * 8];
                o[dt] = __builtin_amdgcn_mfma_f32_16x16x32_bf16(pf, vf, o[dt], 0, 0, 0);
            }
        }
    }

    #pragma unroll
    for (int r = 0; r < 4; ++r) {
        float inv = 1.f / l_run[r];
        int qr = q0 + wid * 16 + lg * 4 + r;
        size_t base = ((size_t)b_ * S + qr) * E + h_ * 64;
        #pragma unroll
        for (int dt = 0; dt < 4; ++dt) {
            float v = o[dt][r] * inv;
            unsigned short hh = f2bf(v);
            AOhi[base + dt * 16 + l16] = hh;
            AOlo[base + dt * 16 + l16] = f2bf(v - bf2f(hh));
        }
    }
}

// ---------------------------------------------------------------------------
extern "C" void kernel_launch(void* const* d_in, const int* in_sizes, int n_in,
                              void* d_out, int out_size, void* d_ws, size_t ws_size,
                              hipStream_t stream)
{
    const float* x   = (const float*)d_in[0];
    const float* w1  = (const float*)d_in[1];
    const float* b1  = (const float*)d_in[2];
    const float* w2  = (const float*)d_in[3];
    const float* b2  = (const float*)d_in[4];
    const float* rel = (const float*)d_in[5];
    float* out = (float*)d_out;

    // workspace (all bf16/ushort), 128 MiB total
    unsigned short* p = (unsigned short*)d_ws;
    const size_t nx = (size_t)M_ROWS * E;        // 8,388,608
    const size_t n1 = (size_t)3 * E * E;         // 3,145,728
    const size_t n2 = (size_t)E * E;             // 1,048,576
    unsigned short* xhi  = p;            p += nx;
    unsigned short* xlo  = p;            p += nx;
    unsigned short* w1hi = p;            p += n1;
    unsigned short* w1lo = p;            p += n1;
    unsigned short* w2hi = p;            p += n2;
    unsigned short* w2lo = p;            p += n2;
    unsigned short* qb   = p;            p += nx; // [B,H,S,D]
    unsigned short* kb   = p;            p += nx; // [B,H,S,D]
    unsigned short* vb   = p;            p += nx; // [B,H,D,S]
    unsigned short* aohi = p;            p += nx; // [B,S,E]
    unsigned short* aolo = p;

    cvt3<<<dim3(6144), dim3(256), 0, stream>>>(x, xhi, xlo, w1, w1hi, w1lo, w2, w2hi, w2lo);

    dim3 g1(3 * E / 128, M_ROWS / 128);
    gemm_mfma<1><<<g1, dim3(256), 0, stream>>>(xhi, xlo, w1hi, w1lo, b1, nullptr,
                                               qb, kb, vb, M_ROWS, 3 * E, E);

    dim3 g2(S / 64, B * H);
    attn_mfma<<<g2, dim3(256), 0, stream>>>(qb, kb, vb, rel, aohi, aolo);

    dim3 g3(E / 128, M_ROWS / 128);
    gemm_mfma<0><<<g3, dim3(256), 0, stream>>>(aohi, aolo, w2hi, w2lo, b2, out,
                                               nullptr, nullptr, nullptr, M_ROWS, E, E);
}